// Round 1
// baseline (1130.194 us; speedup 1.0000x reference)
//
#include <hip/hip_runtime.h>
#include <math.h>

// Problem constants (PointMAE self-attention)
#define DIM   512
#define NH    8
#define HD    64
#define BATCH 8
#define SEQ   1024
#define SCALE 0.125f                       // HD^-0.5
#define MINV  (-3.402823466e38f)           // jnp.finfo(f32).min

// XOR chunk swizzle for [64 rows][64 floats] LDS tiles.
// Element (r,c) -> r*64 + ((c/4) ^ ((r/4)&7))*4 + (c&3).
// Verified conflict-free (<=2-way) for: row-broadcast float4 reads keyed on
// ty (4 rows/wave), 16-row strided float4 reads keyed on tx, and contiguous
// staging writes.
#define SW(r, c) (((r) << 6) + (((((c) >> 2) ^ (((r) >> 2) & 7))) << 2) + ((c) & 3))

// ---------------------------------------------------------------------------
// Kernel 1: QKV projection.  C[m,n] = dot(x[m,:], qkv_w[n,:]) + qkv_b[n]
// m = b*SEQ + t (M=8192), n in [0,1536).  Scatter to q/k/v [b,h,t,d] buffers.
// Block 256 threads = 16x16, 64x64 tile, 4x4 microtile, dot-product inner.
// ---------------------------------------------------------------------------
__global__ __launch_bounds__(256) void qkv_gemm(
    const float* __restrict__ x, const float* __restrict__ w,
    const float* __restrict__ bias,
    float* __restrict__ qb, float* __restrict__ kb, float* __restrict__ vb) {
  __shared__ float As[64 * 64];
  __shared__ float Bs[64 * 64];
  const int tid = threadIdx.x;
  const int tx = tid & 15, ty = tid >> 4;
  const int n0 = blockIdx.x * 64;   // 24 blocks
  const int m0 = blockIdx.y * 64;   // 128 blocks

  float acc[4][4] = {};

  for (int k0 = 0; k0 < DIM; k0 += 64) {
    #pragma unroll
    for (int it = 0; it < 4; ++it) {
      const int r = (tid >> 4) + it * 16;
      const int c = (tid & 15) * 4;
      float4 av = *(const float4*)&x[(size_t)(m0 + r) * DIM + k0 + c];
      *(float4*)&As[SW(r, c)] = av;
      float4 bv = *(const float4*)&w[(size_t)(n0 + r) * DIM + k0 + c];
      *(float4*)&Bs[SW(r, c)] = bv;
    }
    __syncthreads();
    #pragma unroll
    for (int kk = 0; kk < 64; kk += 4) {
      float4 a[4], b[4];
      #pragma unroll
      for (int i = 0; i < 4; ++i) a[i] = *(const float4*)&As[SW(4 * ty + i, kk)];
      #pragma unroll
      for (int j = 0; j < 4; ++j) b[j] = *(const float4*)&Bs[SW(4 * tx + j, kk)];
      #pragma unroll
      for (int i = 0; i < 4; ++i)
        #pragma unroll
        for (int j = 0; j < 4; ++j) {
          acc[i][j] += a[i].x * b[j].x;
          acc[i][j] += a[i].y * b[j].y;
          acc[i][j] += a[i].z * b[j].z;
          acc[i][j] += a[i].w * b[j].w;
        }
    }
    __syncthreads();
  }

  // Epilogue: +bias, scatter. n0 is 64-aligned so which/h are block-uniform.
  const int which = blockIdx.x >> 3;          // 0=q 1=k 2=v
  const int h     = blockIdx.x & 7;
  float* dst = (which == 0) ? qb : (which == 1) ? kb : vb;
  const float4 b4 = *(const float4*)&bias[n0 + 4 * tx];
  #pragma unroll
  for (int i = 0; i < 4; ++i) {
    const int m = m0 + 4 * ty + i;
    const int bb = m >> 10, t = m & 1023;
    float4 o;
    o.x = acc[i][0] + b4.x;
    o.y = acc[i][1] + b4.y;
    o.z = acc[i][2] + b4.z;
    o.w = acc[i][3] + b4.w;
    *(float4*)&dst[((size_t)(((bb << 3) + h) << 10 | t) << 6) + 4 * tx] = o;
  }
}

// ---------------------------------------------------------------------------
// Kernel 2: flash-style masked attention per (b,h).
// Block 256 = 16x16 handles 64 queries; loops over 16 key-tiles of 64.
// Online softmax with finite MINV semantics (matches jnp.where + softmax,
// including fully-masked rows -> uniform).
// ---------------------------------------------------------------------------
__global__ __launch_bounds__(256) void attn_kernel(
    const float* __restrict__ qg, const float* __restrict__ kg,
    const float* __restrict__ vg, const int* __restrict__ mask,
    float* __restrict__ og) {
  __shared__ float Qs[64 * 64];
  __shared__ float Ks[64 * 64];
  __shared__ float Vs[64 * 64];
  __shared__ float Ps[64 * 64];   // P^T: [k][q]

  const int tid = threadIdx.x;
  const int tx = tid & 15, ty = tid >> 4;
  const int q0 = blockIdx.x * 64;       // 16 tiles
  const int bh = blockIdx.y;            // 64
  const int bb = bh >> 3;

  // Stage Q tile once.
  #pragma unroll
  for (int it = 0; it < 4; ++it) {
    const int r = (tid >> 4) + it * 16;
    const int c = (tid & 15) * 4;
    float4 v = *(const float4*)&qg[((size_t)(bh << 10 | (q0 + r)) << 6) + c];
    *(float4*)&Qs[SW(r, c)] = v;
  }

  float m_i[4], l_i[4], oacc[4][4];
  #pragma unroll
  for (int i = 0; i < 4; ++i) {
    m_i[i] = MINV; l_i[i] = 0.f;
    #pragma unroll
    for (int j = 0; j < 4; ++j) oacc[i][j] = 0.f;
  }

  for (int kt = 0; kt < SEQ / 64; ++kt) {
    __syncthreads();   // protect Ks/Vs from previous iteration's readers
    #pragma unroll
    for (int it = 0; it < 4; ++it) {
      const int r = (tid >> 4) + it * 16;
      const int c = (tid & 15) * 4;
      const size_t src = ((size_t)(bh << 10 | (kt * 64 + r)) << 6) + c;
      *(float4*)&Ks[SW(r, c)] = *(const float4*)&kg[src];
      *(float4*)&Vs[SW(r, c)] = *(const float4*)&vg[src];
    }
    __syncthreads();

    // S = Q K^T * SCALE, then mask.
    float s[4][4] = {};
    #pragma unroll
    for (int kk = 0; kk < 64; kk += 4) {
      float4 a[4], b[4];
      #pragma unroll
      for (int i = 0; i < 4; ++i) a[i] = *(const float4*)&Qs[SW(4 * ty + i, kk)];
      #pragma unroll
      for (int j = 0; j < 4; ++j) b[j] = *(const float4*)&Ks[SW(4 * tx + j, kk)];
      #pragma unroll
      for (int i = 0; i < 4; ++i)
        #pragma unroll
        for (int j = 0; j < 4; ++j) {
          s[i][j] += a[i].x * b[j].x;
          s[i][j] += a[i].y * b[j].y;
          s[i][j] += a[i].z * b[j].z;
          s[i][j] += a[i].w * b[j].w;
        }
    }

    float p[4][4];
    #pragma unroll
    for (int i = 0; i < 4; ++i) {
      const int q = q0 + 4 * ty + i;
      const int4 mv =
          *(const int4*)&mask[((size_t)(bb << 10 | q) << 10) + kt * 64 + 4 * tx];
      float s0 = mv.x ? MINV : s[i][0] * SCALE;
      float s1 = mv.y ? MINV : s[i][1] * SCALE;
      float s2 = mv.z ? MINV : s[i][2] * SCALE;
      float s3 = mv.w ? MINV : s[i][3] * SCALE;
      float tm = fmaxf(fmaxf(s0, s1), fmaxf(s2, s3));
      #pragma unroll
      for (int o = 8; o > 0; o >>= 1) tm = fmaxf(tm, __shfl_xor(tm, o));
      const float mn = fmaxf(m_i[i], tm);
      const float alpha = __expf(m_i[i] - mn);
      p[i][0] = __expf(s0 - mn);
      p[i][1] = __expf(s1 - mn);
      p[i][2] = __expf(s2 - mn);
      p[i][3] = __expf(s3 - mn);
      float rs = p[i][0] + p[i][1] + p[i][2] + p[i][3];
      #pragma unroll
      for (int o = 8; o > 0; o >>= 1) rs += __shfl_xor(rs, o);
      l_i[i] = l_i[i] * alpha + rs;
      m_i[i] = mn;
      #pragma unroll
      for (int j = 0; j < 4; ++j) oacc[i][j] *= alpha;
    }

    // Write P^T tile: Ps[k][q].
    #pragma unroll
    for (int j = 0; j < 4; ++j) {
      float4 pv = make_float4(p[0][j], p[1][j], p[2][j], p[3][j]);
      *(float4*)&Ps[SW(4 * tx + j, 4 * ty)] = pv;
    }
    __syncthreads();

    // O += P V  (outer-product over k).
    #pragma unroll 8
    for (int k = 0; k < 64; ++k) {
      float4 pa = *(const float4*)&Ps[SW(k, 4 * ty)];
      float4 vb = *(const float4*)&Vs[SW(k, 4 * tx)];
      const float pr[4] = {pa.x, pa.y, pa.z, pa.w};
      #pragma unroll
      for (int i = 0; i < 4; ++i) {
        oacc[i][0] += pr[i] * vb.x;
        oacc[i][1] += pr[i] * vb.y;
        oacc[i][2] += pr[i] * vb.z;
        oacc[i][3] += pr[i] * vb.w;
      }
    }
  }

  #pragma unroll
  for (int i = 0; i < 4; ++i) {
    const float inv = 1.0f / l_i[i];
    float4 o = make_float4(oacc[i][0] * inv, oacc[i][1] * inv,
                           oacc[i][2] * inv, oacc[i][3] * inv);
    *(float4*)&og[((size_t)(bh << 10 | (q0 + 4 * ty + i)) << 6) + 4 * tx] = o;
  }
}

// ---------------------------------------------------------------------------
// Kernel 3: output projection. out[m,n] = dot(ao[m,:], proj_w[n,:]) + proj_b[n]
// ao gathered from [b,h,t,d]: k = h*64+d, contiguous per 64-aligned k-tile.
// ---------------------------------------------------------------------------
__global__ __launch_bounds__(256) void proj_gemm(
    const float* __restrict__ ao, const float* __restrict__ w,
    const float* __restrict__ bias, float* __restrict__ out) {
  __shared__ float As[64 * 64];
  __shared__ float Bs[64 * 64];
  const int tid = threadIdx.x;
  const int tx = tid & 15, ty = tid >> 4;
  const int n0 = blockIdx.x * 64;   // 8 blocks
  const int m0 = blockIdx.y * 64;   // 128 blocks

  float acc[4][4] = {};

  for (int k0 = 0; k0 < DIM; k0 += 64) {
    const int h = k0 >> 6;
    #pragma unroll
    for (int it = 0; it < 4; ++it) {
      const int r = (tid >> 4) + it * 16;
      const int c = (tid & 15) * 4;
      const int m = m0 + r;
      const int bb = m >> 10, t = m & 1023;
      float4 av =
          *(const float4*)&ao[((size_t)(((bb << 3) + h) << 10 | t) << 6) + c];
      *(float4*)&As[SW(r, c)] = av;
      float4 bv = *(const float4*)&w[(size_t)(n0 + r) * DIM + k0 + c];
      *(float4*)&Bs[SW(r, c)] = bv;
    }
    __syncthreads();
    #pragma unroll
    for (int kk = 0; kk < 64; kk += 4) {
      float4 a[4], b[4];
      #pragma unroll
      for (int i = 0; i < 4; ++i) a[i] = *(const float4*)&As[SW(4 * ty + i, kk)];
      #pragma unroll
      for (int j = 0; j < 4; ++j) b[j] = *(const float4*)&Bs[SW(4 * tx + j, kk)];
      #pragma unroll
      for (int i = 0; i < 4; ++i)
        #pragma unroll
        for (int j = 0; j < 4; ++j) {
          acc[i][j] += a[i].x * b[j].x;
          acc[i][j] += a[i].y * b[j].y;
          acc[i][j] += a[i].z * b[j].z;
          acc[i][j] += a[i].w * b[j].w;
        }
    }
    __syncthreads();
  }

  const float4 b4 = *(const float4*)&bias[n0 + 4 * tx];
  #pragma unroll
  for (int i = 0; i < 4; ++i) {
    const int m = m0 + 4 * ty + i;
    float4 o;
    o.x = acc[i][0] + b4.x;
    o.y = acc[i][1] + b4.y;
    o.z = acc[i][2] + b4.z;
    o.w = acc[i][3] + b4.w;
    *(float4*)&out[(size_t)m * DIM + n0 + 4 * tx] = o;
  }
}

// ---------------------------------------------------------------------------
extern "C" void kernel_launch(void* const* d_in, const int* in_sizes, int n_in,
                              void* d_out, int out_size, void* d_ws,
                              size_t ws_size, hipStream_t stream) {
  const float* x      = (const float*)d_in[0];
  const int*   mask   = (const int*)d_in[1];   // jax bool -> int32 per harness
  const float* qkv_w  = (const float*)d_in[2];
  const float* qkv_b  = (const float*)d_in[3];
  const float* proj_w = (const float*)d_in[4];
  const float* proj_b = (const float*)d_in[5];
  float* out = (float*)d_out;

  // Workspace layout: q | k | v | attn_out, each [B,H,T,D] f32 = 16 MiB.
  const size_t SZ = (size_t)BATCH * NH * SEQ * HD;   // 4,194,304 floats
  float* wsf = (float*)d_ws;
  float* qb = wsf;
  float* kb = wsf + SZ;
  float* vb = wsf + 2 * SZ;
  float* ob = wsf + 3 * SZ;

  qkv_gemm<<<dim3(24, 128), 256, 0, stream>>>(x, qkv_w, qkv_b, qb, kb, vb);
  attn_kernel<<<dim3(SEQ / 64, BATCH * NH), 256, 0, stream>>>(qb, kb, vb, mask, ob);
  proj_gemm<<<dim3(8, 128), 256, 0, stream>>>(ob, proj_w, proj_b, out);
}

// Round 2
// 441.183 us; speedup vs baseline: 2.5617x; 2.5617x over previous
//
#include <hip/hip_runtime.h>
#include <math.h>

// Problem constants (PointMAE self-attention)
#define DIM   512
#define NH    8
#define HD    64
#define BATCH 8
#define SEQ   1024
#define SCALE 0.125f                       // HD^-0.5
#define MINV  (-3.402823466e38f)           // jnp.finfo(f32).min

typedef unsigned short u16;
typedef unsigned int   u32;
typedef unsigned long long u64;
typedef __bf16 bf16x8 __attribute__((ext_vector_type(8)));
typedef float  f32x4  __attribute__((ext_vector_type(4)));

// XOR chunk swizzle for [64 rows][64 floats] fp32 LDS tiles (GEMM kernels).
#define SW(r, c) (((r) << 6) + (((((c) >> 2) ^ (((r) >> 2) & 7))) << 2) + ((c) & 3))

__device__ inline u16 f2bf(float f) {   // fp32 -> bf16 RNE
  u32 u = __builtin_bit_cast(u32, f);
  return (u16)((u + 0x7fffu + ((u >> 16) & 1u)) >> 16);
}

// ---------------------------------------------------------------------------
// Kernel 0: pack mask [B,T,T] int32 -> bitmask [B,T,T/64] uint64.
// One wave per 64 consecutive ints; __ballot forms the 64-bit word.
// ---------------------------------------------------------------------------
__global__ __launch_bounds__(256) void pack_mask(const int* __restrict__ mask,
                                                 u64* __restrict__ bits) {
  const size_t gid = (size_t)blockIdx.x * 256 + threadIdx.x;
  const int lane = threadIdx.x & 63;
  const size_t word = gid >> 6;
  const int v = mask[word * 64 + lane];
  const u64 b = __ballot(v != 0);
  if (lane == 0) bits[word] = b;
}

// ---------------------------------------------------------------------------
// Kernel 1: QKV projection (fp32 compute for accuracy), bf16 output.
// C[m,n] = dot(x[m,:], qkv_w[n,:]) + qkv_b[n]; scatter q/k/v as [b,h,t,d] bf16.
// ---------------------------------------------------------------------------
__global__ __launch_bounds__(256) void qkv_gemm(
    const float* __restrict__ x, const float* __restrict__ w,
    const float* __restrict__ bias,
    u16* __restrict__ qb, u16* __restrict__ kb, u16* __restrict__ vb) {
  __shared__ float As[64 * 64];
  __shared__ float Bs[64 * 64];
  const int tid = threadIdx.x;
  const int tx = tid & 15, ty = tid >> 4;
  const int n0 = blockIdx.x * 64;   // 24 blocks
  const int m0 = blockIdx.y * 64;   // 128 blocks

  float acc[4][4] = {};

  for (int k0 = 0; k0 < DIM; k0 += 64) {
    #pragma unroll
    for (int it = 0; it < 4; ++it) {
      const int r = (tid >> 4) + it * 16;
      const int c = (tid & 15) * 4;
      *(float4*)&As[SW(r, c)] = *(const float4*)&x[(size_t)(m0 + r) * DIM + k0 + c];
      *(float4*)&Bs[SW(r, c)] = *(const float4*)&w[(size_t)(n0 + r) * DIM + k0 + c];
    }
    __syncthreads();
    #pragma unroll
    for (int kk = 0; kk < 64; kk += 4) {
      float4 a[4], b[4];
      #pragma unroll
      for (int i = 0; i < 4; ++i) a[i] = *(const float4*)&As[SW(4 * ty + i, kk)];
      #pragma unroll
      for (int j = 0; j < 4; ++j) b[j] = *(const float4*)&Bs[SW(4 * tx + j, kk)];
      #pragma unroll
      for (int i = 0; i < 4; ++i)
        #pragma unroll
        for (int j = 0; j < 4; ++j) {
          acc[i][j] += a[i].x * b[j].x;
          acc[i][j] += a[i].y * b[j].y;
          acc[i][j] += a[i].z * b[j].z;
          acc[i][j] += a[i].w * b[j].w;
        }
    }
    __syncthreads();
  }

  const int which = blockIdx.x >> 3;          // 0=q 1=k 2=v
  const int h     = blockIdx.x & 7;
  u16* dst = (which == 0) ? qb : (which == 1) ? kb : vb;
  const float4 b4 = *(const float4*)&bias[n0 + 4 * tx];
  #pragma unroll
  for (int i = 0; i < 4; ++i) {
    const int m = m0 + 4 * ty + i;
    const int bb = m >> 10, t = m & 1023;
    ushort4 o;
    o.x = f2bf(acc[i][0] + b4.x);
    o.y = f2bf(acc[i][1] + b4.y);
    o.z = f2bf(acc[i][2] + b4.z);
    o.w = f2bf(acc[i][3] + b4.w);
    *(ushort4*)&dst[((size_t)(((bb << 3) + h) << 10 | t) << 6) + 4 * tx] = o;
  }
}

// ---------------------------------------------------------------------------
// Kernel 2: flash attention with bf16 MFMA (16x16x32), fp32 online softmax.
// Block = 256 thr = 4 waves; 64-query tile; wave w owns q-rows [16w,16w+16).
// LDS tiles stride 72 u16 (144 B rows): every b128 frag read <=2-way banked.
// ---------------------------------------------------------------------------
__global__ __launch_bounds__(256, 4) void attn_mfma(
    const u16* __restrict__ qg, const u16* __restrict__ kg,
    const u16* __restrict__ vg, const u64* __restrict__ bits,
    float* __restrict__ og) {
  __shared__ u16 Qs[64 * 72];   // [q][d]
  __shared__ u16 Ks[64 * 72];   // [k][d]
  __shared__ u16 VT[64 * 72];   // [d][k]  (V transposed)
  __shared__ u16 Ps[64 * 72];   // [q][k]  (P, per-wave-private strips)
  __shared__ u64 msk[64];       // one word per q-row for current k-tile

  const int tid  = threadIdx.x;
  const int lane = tid & 63;
  const int wv   = tid >> 6;           // wave 0..3
  const int lk   = lane & 15;
  const int lq   = lane >> 4;          // 0..3
  const int q0   = blockIdx.x * 64;    // 16 tiles
  const int bh   = blockIdx.y;         // 64
  const int bb   = bh >> 3;

  // Stage Q tile (bf16, [q][d]).
  #pragma unroll
  for (int it = 0; it < 2; ++it) {
    const int idx = it * 256 + tid;
    const int t = idx >> 3, d0 = (idx & 7) * 8;
    *(uint4*)&Qs[t * 72 + d0] =
        *(const uint4*)&qg[((size_t)(bh << 10 | (q0 + t)) << 6) + d0];
  }
  __syncthreads();

  // Hoist Q A-fragments (constant across k-tiles).
  const bf16x8 aq0 = *(const bf16x8*)&Qs[(size_t)(wv * 16 + lk) * 72 + lq * 8];
  const bf16x8 aq1 = *(const bf16x8*)&Qs[(size_t)(wv * 16 + lk) * 72 + 32 + lq * 8];

  f32x4 o_[4];                       // O strip: 4 d-tiles, C-layout
  float m_i[4], l_i[4];
  #pragma unroll
  for (int r = 0; r < 4; ++r) { m_i[r] = MINV; l_i[r] = 0.f; }
  #pragma unroll
  for (int t = 0; t < 4; ++t) o_[t] = (f32x4){0.f, 0.f, 0.f, 0.f};

  #pragma unroll 1
  for (int kt = 0; kt < SEQ / 64; ++kt) {
    __syncthreads();   // protect Ks/VT/msk from previous iteration's readers

    // Stage K tile [k][d].
    #pragma unroll
    for (int it = 0; it < 2; ++it) {
      const int idx = it * 256 + tid;
      const int t = idx >> 3, d0 = (idx & 7) * 8;
      *(uint4*)&Ks[t * 72 + d0] =
          *(const uint4*)&kg[((size_t)(bh << 10 | (kt * 64 + t)) << 6) + d0];
    }
    // Stage V transposed [d][k]: thread owns a k-pair x 8 d's; packed u32 writes.
    {
      const int kp = tid & 31, d0 = (tid >> 5) * 8;
      const int k = 2 * kp;
      const u16* s0 = &vg[((size_t)(bh << 10 | (kt * 64 + k)) << 6) + d0];
      u16 a[8], b[8];
      *(uint4*)a = *(const uint4*)s0;
      *(uint4*)b = *(const uint4*)(s0 + 64);
      #pragma unroll
      for (int j = 0; j < 8; ++j)
        *(u32*)&VT[(size_t)(d0 + j) * 72 + k] = (u32)a[j] | ((u32)b[j] << 16);
    }
    // Stage mask words for this k-tile.
    if (tid < 64)
      msk[tid] = bits[((size_t)(bb << 10 | (q0 + tid)) << 4) + kt];
    __syncthreads();

    // S = Q K^T  (4 16x16 C-tiles per wave along k).
    f32x4 s[4];
    const f32x4 zero = (f32x4){0.f, 0.f, 0.f, 0.f};
    #pragma unroll
    for (int t = 0; t < 4; ++t) {
      const bf16x8 bk0 = *(const bf16x8*)&Ks[(size_t)(t * 16 + lk) * 72 + lq * 8];
      const bf16x8 bk1 = *(const bf16x8*)&Ks[(size_t)(t * 16 + lk) * 72 + 32 + lq * 8];
      f32x4 acc = __builtin_amdgcn_mfma_f32_16x16x32_bf16(aq0, bk0, zero, 0, 0, 0);
      s[t] = __builtin_amdgcn_mfma_f32_16x16x32_bf16(aq1, bk1, acc, 0, 0, 0);
    }

    // Masked online softmax (fp32), write P (bf16) to wave-private Ps strip.
    #pragma unroll
    for (int r = 0; r < 4; ++r) {
      const int qrow = wv * 16 + lq * 4 + r;
      const u64 wd = msk[qrow];
      float sv[4];
      #pragma unroll
      for (int t = 0; t < 4; ++t)
        sv[t] = ((wd >> (t * 16 + lk)) & 1ull) ? MINV : s[t][r] * SCALE;
      float tm = fmaxf(fmaxf(sv[0], sv[1]), fmaxf(sv[2], sv[3]));
      #pragma unroll
      for (int o = 8; o; o >>= 1) tm = fmaxf(tm, __shfl_xor(tm, o));
      const float mn = fmaxf(m_i[r], tm);
      const float alpha = __expf(m_i[r] - mn);
      float rs = 0.f;
      #pragma unroll
      for (int t = 0; t < 4; ++t) {
        const float pv = __expf(sv[t] - mn);
        rs += pv;
        Ps[(size_t)qrow * 72 + t * 16 + lk] = f2bf(pv);
      }
      #pragma unroll
      for (int o = 8; o; o >>= 1) rs += __shfl_xor(rs, o);
      l_i[r] = l_i[r] * alpha + rs;
      m_i[r] = mn;
      #pragma unroll
      for (int t = 0; t < 4; ++t) o_[t][r] *= alpha;
    }

    // O += P V.  A from Ps (own strip, wave-internal ordering only), B from VT.
    const bf16x8 pa0 = *(const bf16x8*)&Ps[(size_t)(wv * 16 + lk) * 72 + lq * 8];
    const bf16x8 pa1 = *(const bf16x8*)&Ps[(size_t)(wv * 16 + lk) * 72 + 32 + lq * 8];
    #pragma unroll
    for (int t = 0; t < 4; ++t) {
      const bf16x8 vb0 = *(const bf16x8*)&VT[(size_t)(t * 16 + lk) * 72 + lq * 8];
      const bf16x8 vb1 = *(const bf16x8*)&VT[(size_t)(t * 16 + lk) * 72 + 32 + lq * 8];
      o_[t] = __builtin_amdgcn_mfma_f32_16x16x32_bf16(pa0, vb0, o_[t], 0, 0, 0);
      o_[t] = __builtin_amdgcn_mfma_f32_16x16x32_bf16(pa1, vb1, o_[t], 0, 0, 0);
    }
  }

  // Epilogue: normalize, store fp32 [b,h,t,d].
  #pragma unroll
  for (int r = 0; r < 4; ++r) {
    const float inv = 1.0f / l_i[r];
    const int q = q0 + wv * 16 + lq * 4 + r;
    #pragma unroll
    for (int t = 0; t < 4; ++t)
      og[((size_t)(bh << 10 | q) << 6) + t * 16 + lk] = o_[t][r] * inv;
  }
}

// ---------------------------------------------------------------------------
// Kernel 3: output projection (fp32). out[m,n] = dot(ao[m,:], proj_w[n,:]) + b
// ---------------------------------------------------------------------------
__global__ __launch_bounds__(256) void proj_gemm(
    const float* __restrict__ ao, const float* __restrict__ w,
    const float* __restrict__ bias, float* __restrict__ out) {
  __shared__ float As[64 * 64];
  __shared__ float Bs[64 * 64];
  const int tid = threadIdx.x;
  const int tx = tid & 15, ty = tid >> 4;
  const int n0 = blockIdx.x * 64;   // 8 blocks
  const int m0 = blockIdx.y * 64;   // 128 blocks

  float acc[4][4] = {};

  for (int k0 = 0; k0 < DIM; k0 += 64) {
    const int h = k0 >> 6;
    #pragma unroll
    for (int it = 0; it < 4; ++it) {
      const int r = (tid >> 4) + it * 16;
      const int c = (tid & 15) * 4;
      const int m = m0 + r;
      const int bb = m >> 10, t = m & 1023;
      *(float4*)&As[SW(r, c)] =
          *(const float4*)&ao[((size_t)(((bb << 3) + h) << 10 | t) << 6) + c];
      *(float4*)&Bs[SW(r, c)] = *(const float4*)&w[(size_t)(n0 + r) * DIM + k0 + c];
    }
    __syncthreads();
    #pragma unroll
    for (int kk = 0; kk < 64; kk += 4) {
      float4 a[4], b[4];
      #pragma unroll
      for (int i = 0; i < 4; ++i) a[i] = *(const float4*)&As[SW(4 * ty + i, kk)];
      #pragma unroll
      for (int j = 0; j < 4; ++j) b[j] = *(const float4*)&Bs[SW(4 * tx + j, kk)];
      #pragma unroll
      for (int i = 0; i < 4; ++i)
        #pragma unroll
        for (int j = 0; j < 4; ++j) {
          acc[i][j] += a[i].x * b[j].x;
          acc[i][j] += a[i].y * b[j].y;
          acc[i][j] += a[i].z * b[j].z;
          acc[i][j] += a[i].w * b[j].w;
        }
    }
    __syncthreads();
  }

  const float4 b4 = *(const float4*)&bias[n0 + 4 * tx];
  #pragma unroll
  for (int i = 0; i < 4; ++i) {
    const int m = m0 + 4 * ty + i;
    float4 o;
    o.x = acc[i][0] + b4.x;
    o.y = acc[i][1] + b4.y;
    o.z = acc[i][2] + b4.z;
    o.w = acc[i][3] + b4.w;
    *(float4*)&out[(size_t)m * DIM + n0 + 4 * tx] = o;
  }
}

// ---------------------------------------------------------------------------
extern "C" void kernel_launch(void* const* d_in, const int* in_sizes, int n_in,
                              void* d_out, int out_size, void* d_ws,
                              size_t ws_size, hipStream_t stream) {
  const float* x      = (const float*)d_in[0];
  const int*   mask   = (const int*)d_in[1];   // jax bool -> int32
  const float* qkv_w  = (const float*)d_in[2];
  const float* qkv_b  = (const float*)d_in[3];
  const float* proj_w = (const float*)d_in[4];
  const float* proj_b = (const float*)d_in[5];
  float* out = (float*)d_out;

  // Workspace: q|k|v bf16 [B,H,T,D] (8 MB ea) | ob fp32 (16 MB) | bits (1 MB).
  const size_t SZ = (size_t)BATCH * NH * SEQ * HD;   // 4,194,304
  u16* qb = (u16*)d_ws;
  u16* kb = qb + SZ;
  u16* vb = kb + SZ;
  float* ob = (float*)(vb + SZ);
  u64* bits = (u64*)(ob + SZ);

  pack_mask<<<(BATCH * SEQ * SEQ) / 256, 256, 0, stream>>>(mask, bits);
  qkv_gemm<<<dim3(24, 128), 256, 0, stream>>>(x, qkv_w, qkv_b, qb, kb, vb);
  attn_mfma<<<dim3(SEQ / 64, BATCH * NH), 256, 0, stream>>>(qb, kb, vb, bits, ob);
  proj_gemm<<<dim3(8, 128), 256, 0, stream>>>(ob, proj_w, proj_b, out);
}

// Round 3
// 244.034 us; speedup vs baseline: 4.6313x; 1.8079x over previous
//
#include <hip/hip_runtime.h>
#include <math.h>

// Problem constants (PointMAE self-attention)
#define DIM   512
#define NH    8
#define HD    64
#define BATCH 8
#define SEQ   1024
#define SCALE 0.125f                       // HD^-0.5
#define MINV  (-3.402823466e38f)           // jnp.finfo(f32).min

typedef unsigned short u16;
typedef unsigned int   u32;
typedef unsigned long long u64;
typedef __bf16 bf16x8 __attribute__((ext_vector_type(8)));
typedef float  f32x4  __attribute__((ext_vector_type(4)));

__device__ inline u16 f2bf(float f) {   // fp32 -> bf16 RNE
  u32 u = __builtin_bit_cast(u32, f);
  return (u16)((u + 0x7fffu + ((u >> 16) & 1u)) >> 16);
}
__device__ inline float bf2f(u16 h) {
  return __builtin_bit_cast(float, (u32)h << 16);
}

// Async global->LDS, 16 B per lane. LDS side must be base + lane*16.
__device__ inline void a16(const u16* g, u16* l) {
  __builtin_amdgcn_global_load_lds(
      (const __attribute__((address_space(1))) u32*)g,
      (__attribute__((address_space(3))) u32*)l, 16, 0, 0);
}

// Tiled fragment layout for K=512 tensors: elt(m,k) ->
//   (m>>4)*8192 + (k>>3)*128 + (m&15)*8 + (k&7)
// A 16-row x 32-k slab (one MFMA fragment tile) is 1 KB contiguous in exact
// lane order (lane = lq*16+lk -> lane*8 elts), so global_load_lds stages it
// coalesced AND ds_read_b128 frag reads are the canonical conflict-free
// base+lane*16 pattern.

// ---------------------------------------------------------------------------
// Kernel 0a: pack mask [B,T,T] int32 -> bitmask uint64 via ballot.
// ---------------------------------------------------------------------------
__global__ __launch_bounds__(256) void pack_mask(const int* __restrict__ mask,
                                                 u64* __restrict__ bits) {
  const size_t gid = (size_t)blockIdx.x * 256 + threadIdx.x;
  const int lane = threadIdx.x & 63;
  const size_t word = gid >> 6;
  const int v = mask[word * 64 + lane];
  const u64 b = __ballot(v != 0);
  if (lane == 0) bits[word] = b;
}

// ---------------------------------------------------------------------------
// Kernel 0b: decompose fp32 [R][512] -> bf16 hi/lo in tiled fragment layout.
// One block per 16-row group; writes are lane-contiguous 16 B.
// ---------------------------------------------------------------------------
__global__ __launch_bounds__(256) void decompose(const float* __restrict__ src,
                                                 u16* __restrict__ hi,
                                                 u16* __restrict__ lo) {
  const int rg = blockIdx.x;
  const int t = threadIdx.x;
  const float* s = src + (size_t)rg * 16 * DIM;
  u16* ph = hi + (size_t)rg * 8192;
  u16* pl = lo + (size_t)rg * 8192;
  #pragma unroll
  for (int c = 0; c < 4; ++c) {
    const int cid = c * 256 + t;        // chunk id = kc*16 + row
    const int row = cid & 15, kc = cid >> 4;
    float f[8];
    *(float4*)&f[0] = *(const float4*)&s[row * DIM + kc * 8];
    *(float4*)&f[4] = *(const float4*)&s[row * DIM + kc * 8 + 4];
    u16 hv[8], lv[8];
    #pragma unroll
    for (int j = 0; j < 8; ++j) {
      hv[j] = f2bf(f[j]);
      lv[j] = f2bf(f[j] - bf2f(hv[j]));
    }
    *(uint4*)&ph[(size_t)cid * 8] = *(const uint4*)hv;
    *(uint4*)&pl[(size_t)cid * 8] = *(const uint4*)lv;
  }
}

// ---------------------------------------------------------------------------
// Kernel 1/3: split-bf16 MFMA GEMM.  C = A·B^T (+bias), fp32-accurate via
// 3 passes (AhBh + AhBl + AlBh).  A [M][512], B [N][512] both in tiled hi/lo
// layout.  Block: 128x128 tile, 4 waves x 64x64, BK=32, 16 k-iters.
// QKV=true: scatter bf16 q/k/v [b,h,t,d].  QKV=false: fp32 out [m][512].
// ---------------------------------------------------------------------------
template <bool QKV>
__global__ __launch_bounds__(256) void mfma_gemm(
    const u16* __restrict__ Agh, const u16* __restrict__ Agl,
    const u16* __restrict__ Bgh, const u16* __restrict__ Bgl,
    const float* __restrict__ bias, void* __restrict__ out0,
    u16* __restrict__ kb, u16* __restrict__ vb) {
  __shared__ u16 sAh[4096];   // 8 m-tiles x 512 elts (16 rows x 32 k)
  __shared__ u16 sAl[4096];
  __shared__ u16 sBh[4096];
  __shared__ u16 sBl[4096];

  const int tid = threadIdx.x;
  const int lane = tid & 63;
  const int wv = tid >> 6;
  const int lk = lane & 15, lq = lane >> 4;
  const int n0 = blockIdx.x * 128, m0 = blockIdx.y * 128;
  const int wm = (wv & 1) * 4;     // wave's m-tile base (tiles)
  const int wn = (wv >> 1) * 4;    // wave's n-tile base

  const u16* gAh = Agh + (size_t)(m0 >> 4) * 8192 + lane * 8;
  const u16* gAl = Agl + (size_t)(m0 >> 4) * 8192 + lane * 8;
  const u16* gBh = Bgh + (size_t)(n0 >> 4) * 8192 + lane * 8;
  const u16* gBl = Bgl + (size_t)(n0 >> 4) * 8192 + lane * 8;

  f32x4 acc[4][4];
  #pragma unroll
  for (int i = 0; i < 4; ++i)
    #pragma unroll
    for (int j = 0; j < 4; ++j) acc[i][j] = (f32x4){0.f, 0.f, 0.f, 0.f};

  #pragma unroll 1
  for (int ki = 0; ki < 16; ++ki) {
    __syncthreads();
    #pragma unroll
    for (int it = 0; it < 2; ++it) {
      const int t = it * 4 + wv;                  // tile staged by this wave
      const size_t go = (size_t)t * 8192 + ki * 512;
      const int lo_ = t * 512 + lane * 8;
      a16(gAh + go, &sAh[lo_]);
      a16(gAl + go, &sAl[lo_]);
      a16(gBh + go, &sBh[lo_]);
      a16(gBl + go, &sBl[lo_]);
    }
    __syncthreads();

    bf16x8 ah[4], al[4], bh[4], bl[4];
    #pragma unroll
    for (int i = 0; i < 4; ++i) {
      ah[i] = *(const bf16x8*)&sAh[(wm + i) * 512 + lane * 8];
      al[i] = *(const bf16x8*)&sAl[(wm + i) * 512 + lane * 8];
      bh[i] = *(const bf16x8*)&sBh[(wn + i) * 512 + lane * 8];
      bl[i] = *(const bf16x8*)&sBl[(wn + i) * 512 + lane * 8];
    }
    #pragma unroll
    for (int i = 0; i < 4; ++i)
      #pragma unroll
      for (int j = 0; j < 4; ++j) {
        acc[i][j] = __builtin_amdgcn_mfma_f32_16x16x32_bf16(ah[i], bh[j], acc[i][j], 0, 0, 0);
        acc[i][j] = __builtin_amdgcn_mfma_f32_16x16x32_bf16(ah[i], bl[j], acc[i][j], 0, 0, 0);
        acc[i][j] = __builtin_amdgcn_mfma_f32_16x16x32_bf16(al[i], bh[j], acc[i][j], 0, 0, 0);
      }
  }

  // Epilogue. C/D layout: col = lk, row = lq*4 + r.
  #pragma unroll
  for (int j = 0; j < 4; ++j) {
    const int n = n0 + (wn + j) * 16 + lk;
    const float bv = bias[n];
    #pragma unroll
    for (int i = 0; i < 4; ++i) {
      #pragma unroll
      for (int r = 0; r < 4; ++r) {
        const int m = m0 + (wm + i) * 16 + lq * 4 + r;
        const float v = acc[i][j][r] + bv;
        if (QKV) {
          const int which = n >> 9, h = (n >> 6) & 7, d = n & 63;
          u16* dst = (which == 0) ? (u16*)out0 : (which == 1) ? kb : vb;
          const int b = m >> 10, tok = m & 1023;
          dst[(((size_t)((b << 3) + h) << 10 | tok) << 6) + d] = f2bf(v);
        } else {
          ((float*)out0)[(size_t)m * DIM + n] = v;
        }
      }
    }
  }
}

// ---------------------------------------------------------------------------
// Kernel 2: flash attention, bf16 MFMA, fp32 online softmax.
// Epilogue writes O as tiled hi/lo bf16 (proj GEMM's A operand).
// ---------------------------------------------------------------------------
__global__ __launch_bounds__(256, 4) void attn_mfma(
    const u16* __restrict__ qg, const u16* __restrict__ kg,
    const u16* __restrict__ vg, const u64* __restrict__ bits,
    u16* __restrict__ ohi, u16* __restrict__ olo) {
  __shared__ u16 Qs[64 * 72];   // [q][d]
  __shared__ u16 Ks[64 * 72];   // [k][d]
  __shared__ u16 VT[64 * 72];   // [d][k]
  __shared__ u16 Ps[64 * 72];   // [q][k]
  __shared__ u64 msk[64];

  const int tid  = threadIdx.x;
  const int lane = tid & 63;
  const int wv   = tid >> 6;
  const int lk   = lane & 15;
  const int lq   = lane >> 4;
  const int q0   = blockIdx.x * 64;
  const int bh   = blockIdx.y;
  const int bb   = bh >> 3;

  #pragma unroll
  for (int it = 0; it < 2; ++it) {
    const int idx = it * 256 + tid;
    const int t = idx >> 3, d0 = (idx & 7) * 8;
    *(uint4*)&Qs[t * 72 + d0] =
        *(const uint4*)&qg[((size_t)(bh << 10 | (q0 + t)) << 6) + d0];
  }
  __syncthreads();

  const bf16x8 aq0 = *(const bf16x8*)&Qs[(size_t)(wv * 16 + lk) * 72 + lq * 8];
  const bf16x8 aq1 = *(const bf16x8*)&Qs[(size_t)(wv * 16 + lk) * 72 + 32 + lq * 8];

  f32x4 o_[4];
  float m_i[4], l_i[4];
  #pragma unroll
  for (int r = 0; r < 4; ++r) { m_i[r] = MINV; l_i[r] = 0.f; }
  #pragma unroll
  for (int t = 0; t < 4; ++t) o_[t] = (f32x4){0.f, 0.f, 0.f, 0.f};

  #pragma unroll 1
  for (int kt = 0; kt < SEQ / 64; ++kt) {
    __syncthreads();

    #pragma unroll
    for (int it = 0; it < 2; ++it) {
      const int idx = it * 256 + tid;
      const int t = idx >> 3, d0 = (idx & 7) * 8;
      *(uint4*)&Ks[t * 72 + d0] =
          *(const uint4*)&kg[((size_t)(bh << 10 | (kt * 64 + t)) << 6) + d0];
    }
    {
      const int kp = tid & 31, d0 = (tid >> 5) * 8;
      const int k = 2 * kp;
      const u16* s0 = &vg[((size_t)(bh << 10 | (kt * 64 + k)) << 6) + d0];
      u16 a[8], b[8];
      *(uint4*)a = *(const uint4*)s0;
      *(uint4*)b = *(const uint4*)(s0 + 64);
      #pragma unroll
      for (int j = 0; j < 8; ++j)
        *(u32*)&VT[(size_t)(d0 + j) * 72 + k] = (u32)a[j] | ((u32)b[j] << 16);
    }
    if (tid < 64)
      msk[tid] = bits[((size_t)(bb << 10 | (q0 + tid)) << 4) + kt];
    __syncthreads();

    f32x4 s[4];
    const f32x4 zero = (f32x4){0.f, 0.f, 0.f, 0.f};
    #pragma unroll
    for (int t = 0; t < 4; ++t) {
      const bf16x8 bk0 = *(const bf16x8*)&Ks[(size_t)(t * 16 + lk) * 72 + lq * 8];
      const bf16x8 bk1 = *(const bf16x8*)&Ks[(size_t)(t * 16 + lk) * 72 + 32 + lq * 8];
      f32x4 acc = __builtin_amdgcn_mfma_f32_16x16x32_bf16(aq0, bk0, zero, 0, 0, 0);
      s[t] = __builtin_amdgcn_mfma_f32_16x16x32_bf16(aq1, bk1, acc, 0, 0, 0);
    }

    #pragma unroll
    for (int r = 0; r < 4; ++r) {
      const int qrow = wv * 16 + lq * 4 + r;
      const u64 wd = msk[qrow];
      float sv[4];
      #pragma unroll
      for (int t = 0; t < 4; ++t)
        sv[t] = ((wd >> (t * 16 + lk)) & 1ull) ? MINV : s[t][r] * SCALE;
      float tm = fmaxf(fmaxf(sv[0], sv[1]), fmaxf(sv[2], sv[3]));
      #pragma unroll
      for (int o = 8; o; o >>= 1) tm = fmaxf(tm, __shfl_xor(tm, o));
      const float mn = fmaxf(m_i[r], tm);
      const float alpha = __expf(m_i[r] - mn);
      float rs = 0.f;
      #pragma unroll
      for (int t = 0; t < 4; ++t) {
        const float pv = __expf(sv[t] - mn);
        rs += pv;
        Ps[(size_t)qrow * 72 + t * 16 + lk] = f2bf(pv);
      }
      #pragma unroll
      for (int o = 8; o; o >>= 1) rs += __shfl_xor(rs, o);
      l_i[r] = l_i[r] * alpha + rs;
      m_i[r] = mn;
      #pragma unroll
      for (int t = 0; t < 4; ++t) o_[t][r] *= alpha;
    }

    const bf16x8 pa0 = *(const bf16x8*)&Ps[(size_t)(wv * 16 + lk) * 72 + lq * 8];
    const bf16x8 pa1 = *(const bf16x8*)&Ps[(size_t)(wv * 16 + lk) * 72 + 32 + lq * 8];
    #pragma unroll
    for (int t = 0; t < 4; ++t) {
      const bf16x8 vb0 = *(const bf16x8*)&VT[(size_t)(t * 16 + lk) * 72 + lq * 8];
      const bf16x8 vb1 = *(const bf16x8*)&VT[(size_t)(t * 16 + lk) * 72 + 32 + lq * 8];
      o_[t] = __builtin_amdgcn_mfma_f32_16x16x32_bf16(pa0, vb0, o_[t], 0, 0, 0);
      o_[t] = __builtin_amdgcn_mfma_f32_16x16x32_bf16(pa1, vb1, o_[t], 0, 0, 0);
    }
  }

  // Epilogue: normalize; emit tiled hi/lo for proj GEMM (m = b*1024+tok,
  // k = h*64+d).
  const int b = bh >> 3, h = bh & 7;
  #pragma unroll
  for (int r = 0; r < 4; ++r) {
    const float inv = 1.0f / l_i[r];
    const int tok = q0 + wv * 16 + lq * 4 + r;
    const int m = (b << 10) | tok;
    const size_t rgo = (size_t)(m >> 4) * 8192 + (size_t)(m & 15) * 8;
    #pragma unroll
    for (int t = 0; t < 4; ++t) {
      const int d = t * 16 + lk;
      const int k = (h << 6) | d;
      const float v = o_[t][r] * inv;
      const u16 hv = f2bf(v);
      const size_t off = rgo + (size_t)(k >> 3) * 128 + (k & 7);
      ohi[off] = hv;
      olo[off] = f2bf(v - bf2f(hv));
    }
  }
}

// ---------------------------------------------------------------------------
extern "C" void kernel_launch(void* const* d_in, const int* in_sizes, int n_in,
                              void* d_out, int out_size, void* d_ws,
                              size_t ws_size, hipStream_t stream) {
  const float* x      = (const float*)d_in[0];
  const int*   mask   = (const int*)d_in[1];   // jax bool -> int32
  const float* qkv_w  = (const float*)d_in[2];
  const float* qkv_b  = (const float*)d_in[3];
  const float* proj_w = (const float*)d_in[4];
  const float* proj_b = (const float*)d_in[5];
  float* out = (float*)d_out;

  // Workspace (~64 MB): bits | qb kb vb | xhi xlo | ohi olo | wqh wql | wph wpl
  const size_t SZ = (size_t)BATCH * NH * SEQ * HD;   // 4,194,304 elts
  u64* bits = (u64*)d_ws;                            // 1 MB (131072 u64)
  u16* qb  = (u16*)(bits + 131072);
  u16* kb  = qb + SZ;
  u16* vb  = kb + SZ;
  u16* xhi = vb + SZ;
  u16* xlo = xhi + SZ;          // x: 8192x512 = SZ
  u16* ohi = xlo + SZ;
  u16* olo = ohi + SZ;
  u16* wqh = olo + SZ;
  u16* wql = wqh + 1536 * 512;
  u16* wph = wql + 1536 * 512;
  u16* wpl = wph + 512 * 512;

  pack_mask<<<(BATCH * SEQ * SEQ) / 256, 256, 0, stream>>>(mask, bits);
  decompose<<<8192 / 16, 256, 0, stream>>>(x, xhi, xlo);
  decompose<<<1536 / 16, 256, 0, stream>>>(qkv_w, wqh, wql);
  decompose<<<512 / 16, 256, 0, stream>>>(proj_w, wph, wpl);

  mfma_gemm<true><<<dim3(12, 64), 256, 0, stream>>>(
      xhi, xlo, wqh, wql, qkv_b, qb, kb, vb);
  attn_mfma<<<dim3(SEQ / 64, BATCH * NH), 256, 0, stream>>>(
      qb, kb, vb, bits, ohi, olo);
  mfma_gemm<false><<<dim3(4, 64), 256, 0, stream>>>(
      ohi, olo, wph, wpl, proj_b, out, nullptr, nullptr);
}